// Round 1
// baseline (3392.757 us; speedup 1.0000x reference)
//
#include <hip/hip_runtime.h>
#include <cmath>

#define KNN 20
#define NPTS 4096
#define BATCH 2
#define SLOPE 0.2f
#define BNEPS 1e-5f

static __device__ __host__ inline int imin(int a, int b) { return a < b ? a : b; }

// ---------------- utility kernels ----------------
__global__ void zero_kernel(float* p, int n) {
  int i = blockIdx.x * 256 + threadIdx.x;
  if (i < n) p[i] = 0.f;
}

// x (B,3,N) -> xb (B,N,3)
__global__ void xtrans_kernel(const float* __restrict__ x, float* __restrict__ xb) {
  int i = blockIdx.x * 256 + threadIdx.x;
  if (i < BATCH * 3 * NPTS) {
    int b = i / (3 * NPTS);
    int r = i - b * 3 * NPTS;
    int c = r / NPTS;
    int n = r - c * NPTS;
    xb[((size_t)b * NPTS + n) * 3 + c] = x[i];
  }
}

// w (O,I) -> wt (I,O)
__global__ void wtrans_kernel(const float* __restrict__ w, float* __restrict__ wt, int O, int I) {
  int i = blockIdx.x * 256 + threadIdx.x;
  if (i < O * I) {
    int o = i / I, j = i - o * I;
    wt[(size_t)j * O + o] = w[i];
  }
}

// squared norms per point (both batches; X base covers B*N rows of `stride`)
__global__ void xx_kernel(const float* __restrict__ X, int stride, int C, float* __restrict__ xx) {
  int i = blockIdx.x * 256 + threadIdx.x;
  if (i < BATCH * NPTS) {
    const float* r = X + (size_t)i * stride;
    float s = 0.f;
    for (int c = 0; c < C; ++c) s += r[c] * r[c];
    xx[i] = s;
  }
}

// ---------------- distance slab GEMM ----------------
// neg_d[n][m] = 2*inner(n,m) - xx[n] - xx[m]; writes rows [n0, n0+rows) of one batch.
// grid: (NPTS/64, rows/64), block 256 (16x16, 4x4 micro)
__global__ void dist_kernel(const float* __restrict__ X, int stride, int C,
                            const float* __restrict__ xx, float* __restrict__ dist, int n0) {
  __shared__ float sN[64][17];
  __shared__ float sM[64][17];
  int t = threadIdx.x;
  int tx = t & 15, ty = t >> 4;
  int m0 = blockIdx.x * 64;
  int nt0 = n0 + blockIdx.y * 64;
  float acc[4][4];
#pragma unroll
  for (int i = 0; i < 4; ++i)
#pragma unroll
    for (int j = 0; j < 4; ++j) acc[i][j] = 0.f;

  for (int c0 = 0; c0 < C; c0 += 16) {
    for (int e = t; e < 64 * 16; e += 256) {
      int r = e >> 4, cc = e & 15;
      int c = c0 + cc;
      float vn = 0.f, vm = 0.f;
      if (c < C) {
        vn = X[(size_t)(nt0 + r) * stride + c];
        vm = X[(size_t)(m0 + r) * stride + c];
      }
      sN[r][cc] = vn;
      sM[r][cc] = vm;
    }
    __syncthreads();
    int cmax = imin(16, C - c0);
    for (int cc = 0; cc < cmax; ++cc) {
      float a[4], bv[4];
#pragma unroll
      for (int i = 0; i < 4; ++i) a[i] = sN[ty * 4 + i][cc];
#pragma unroll
      for (int j = 0; j < 4; ++j) bv[j] = sM[tx * 4 + j][cc];
#pragma unroll
      for (int i = 0; i < 4; ++i)
#pragma unroll
        for (int j = 0; j < 4; ++j) acc[i][j] += a[i] * bv[j];
    }
    __syncthreads();
  }
#pragma unroll
  for (int i = 0; i < 4; ++i) {
    int gn = nt0 + ty * 4 + i;
    float xn = xx[gn];
#pragma unroll
    for (int j = 0; j < 4; ++j) {
      int gm = m0 + tx * 4 + j;
      dist[(size_t)(gn - n0) * NPTS + gm] = 2.f * acc[i][j] - xn - xx[gm];
    }
  }
}

// ---------------- top-k (20 iterations of argmax, tie -> lower index) ----------------
// grid: rows, block 256
__global__ void topk_kernel(const float* __restrict__ dist, int* __restrict__ idxout, int n0) {
  __shared__ float vals[NPTS];
  __shared__ float wv[4];
  __shared__ int wi[4];
  int t = threadIdx.x;
  const float* d = dist + (size_t)blockIdx.x * NPTS;
  for (int i = t; i < NPTS; i += 256) vals[i] = d[i];
  __syncthreads();
  int lane = t & 63, wid = t >> 6;
  for (int it = 0; it < KNN; ++it) {
    float bv = -__builtin_inff();
    int bi = NPTS;
    for (int i = t; i < NPTS; i += 256) {
      float v = vals[i];
      if (v > bv || (v == bv && i < bi)) { bv = v; bi = i; }
    }
#pragma unroll
    for (int s = 32; s > 0; s >>= 1) {
      float ov = __shfl_xor(bv, s);
      int oi = __shfl_xor(bi, s);
      if (ov > bv || (ov == bv && oi < bi)) { bv = ov; bi = oi; }
    }
    if (lane == 0) { wv[wid] = bv; wi[wid] = bi; }
    __syncthreads();
    if (t == 0) {
      float fv = wv[0]; int fi = wi[0];
      for (int q = 1; q < 4; ++q)
        if (wv[q] > fv || (wv[q] == fv && wi[q] < fi)) { fv = wv[q]; fi = wi[q]; }
      idxout[(size_t)(n0 + blockIdx.x) * KNN + it] = fi;
      vals[fi] = -__builtin_inff();
    }
    __syncthreads();
  }
}

// ---------------- edge conv: h[k,o] = nbr_k.w1_o + c.(w2_o - w1_o); max/sum/sumsq over k ----
// block 128 threads = 2 points x 64 lanes; thread handles NO channels (o = tl + 64q)
template <int NO>
__global__ void edgeconv_kernel(const float* __restrict__ X, int stride, int C, int O,
                                const float* __restrict__ Wt,  // (2C, O)
                                const int* __restrict__ idx,
                                float* __restrict__ hmax,
                                float* __restrict__ ssum, float* __restrict__ ssq) {
  extern __shared__ float lds[];
  float* cbuf = lds;                   // 2*C
  float* nbr = cbuf + 2 * C;           // 2*KNN*C
  float* wsh = nbr + 2 * KNN * C;      // 16*O
  int* sidx = (int*)(wsh + 16 * O);    // 2*KNN
  int t = threadIdx.x;
  int p = t >> 6, tl = t & 63;
  int n = blockIdx.x * 2 + p;
  int b = blockIdx.y;
  size_t pt = (size_t)b * NPTS + n;
  const float* Xb = X + (size_t)b * NPTS * stride;

  if (tl < KNN) sidx[p * KNN + tl] = idx[pt * KNN + tl];
  for (int j = tl; j < C; j += 64) cbuf[p * C + j] = Xb[(size_t)n * stride + j];
  __syncthreads();
  for (int k = 0; k < KNN; ++k) {
    int gm = sidx[p * KNN + k];
    for (int j = tl; j < C; j += 64) nbr[(p * KNN + k) * C + j] = Xb[(size_t)gm * stride + j];
  }
  __syncthreads();

  float acc[KNN][NO];
#pragma unroll
  for (int k = 0; k < KNN; ++k)
#pragma unroll
    for (int q = 0; q < NO; ++q) acc[k][q] = 0.f;
  float base[NO];
#pragma unroll
  for (int q = 0; q < NO; ++q) base[q] = 0.f;

  // phase A: w1 rows (j in [0,C))
  for (int j0 = 0; j0 < C; j0 += 16) {
    int jc = imin(16, C - j0);
    for (int e = t; e < jc * O; e += 128) wsh[e] = Wt[(size_t)j0 * O + e];
    __syncthreads();
    for (int jj = 0; jj < jc; ++jj) {
      int j = j0 + jj;
      float w[NO];
#pragma unroll
      for (int q = 0; q < NO; ++q) w[q] = wsh[jj * O + tl + 64 * q];
      float cj = cbuf[p * C + j];
#pragma unroll
      for (int q = 0; q < NO; ++q) base[q] -= cj * w[q];
#pragma unroll
      for (int k = 0; k < KNN; ++k) {
        float nv = nbr[(p * KNN + k) * C + j];
#pragma unroll
        for (int q = 0; q < NO; ++q) acc[k][q] += nv * w[q];
      }
    }
    __syncthreads();
  }
  // phase B: w2 rows (j in [C,2C))
  for (int j0 = 0; j0 < C; j0 += 16) {
    int jc = imin(16, C - j0);
    for (int e = t; e < jc * O; e += 128) wsh[e] = Wt[(size_t)(C + j0) * O + e];
    __syncthreads();
    for (int jj = 0; jj < jc; ++jj) {
      float cj = cbuf[p * C + j0 + jj];
#pragma unroll
      for (int q = 0; q < NO; ++q) base[q] += cj * wsh[jj * O + tl + 64 * q];
    }
    __syncthreads();
  }

#pragma unroll
  for (int q = 0; q < NO; ++q) {
    int o = tl + 64 * q;
    float m = -__builtin_inff(), s1 = 0.f, s2 = 0.f;
#pragma unroll
    for (int k = 0; k < KNN; ++k) {
      float h = acc[k][q] + base[q];
      m = fmaxf(m, h);
      s1 += h;
      s2 += h * h;
    }
    hmax[pt * O + o] = m;
    atomicAdd(&ssum[o], s1);
    atomicAdd(&ssq[o], s2);
  }
}

// ---------------- BN finalize: s,t per channel ----------------
__global__ void bn_finalize(const float* __restrict__ ssum, const float* __restrict__ ssq,
                            const float* __restrict__ g, const float* __restrict__ bb,
                            float invcount, int O, float* __restrict__ s_out, float* __restrict__ t_out) {
  int o = blockIdx.x * 256 + threadIdx.x;
  if (o < O) {
    float mean = ssum[o] * invcount;
    float var = ssq[o] * invcount - mean * mean;
    float s = g[o] * rsqrtf(var + BNEPS);
    s_out[o] = s;
    t_out[o] = bb[o] - mean * s;
  }
}

// y = leaky(hmax*s+t) into feat column slice
__global__ void apply_kernel(const float* __restrict__ hmax, const float* __restrict__ s,
                             const float* __restrict__ tt, float* __restrict__ feat,
                             int colOff, int logO, int total) {
  int i = blockIdx.x * 256 + threadIdx.x;
  if (i >= total) return;
  int O = 1 << logO;
  int o = i & (O - 1);
  int pp = i >> logO;
  float v = hmax[i] * s[o] + tt[o];
  feat[(size_t)pp * 512 + colOff + o] = v > 0.f ? v : SLOPE * v;
}

// ---------------- final FC: h5 = cat(512) @ W5t(512,1024) + stats ----------------
// grid (B*N/16, 4), block 256; thread owns one o in its 256-slice, 16 points
__global__ void fc_kernel(const float* __restrict__ feat, const float* __restrict__ w5t,
                          float* __restrict__ h5, float* __restrict__ ssum, float* __restrict__ ssq) {
  __shared__ float srow[16][512];
  __shared__ float wsh[16][256];
  int t = threadIdx.x;
  int p0 = blockIdx.x * 16;
  int o0 = blockIdx.y * 256;
  for (int e = t; e < 16 * 512; e += 256) {
    int p = e >> 9, j = e & 511;
    srow[p][j] = feat[(size_t)(p0 + p) * 512 + j];
  }
  float acc[16];
#pragma unroll
  for (int p = 0; p < 16; ++p) acc[p] = 0.f;
  for (int j0 = 0; j0 < 512; j0 += 16) {
    __syncthreads();
    for (int jj = 0; jj < 16; ++jj) wsh[jj][t] = w5t[(size_t)(j0 + jj) * 1024 + o0 + t];
    __syncthreads();
    for (int jj = 0; jj < 16; ++jj) {
      float w = wsh[jj][t];
#pragma unroll
      for (int p = 0; p < 16; ++p) acc[p] += srow[p][j0 + jj] * w;
    }
  }
  float s1 = 0.f, s2 = 0.f;
#pragma unroll
  for (int p = 0; p < 16; ++p) {
    h5[(size_t)(p0 + p) * 1024 + o0 + t] = acc[p];
    s1 += acc[p];
    s2 += acc[p] * acc[p];
  }
  atomicAdd(&ssum[o0 + t], s1);
  atomicAdd(&ssq[o0 + t], s2);
}

// out[b][o][n] = leaky(h5[b][n][o]*s+t), transposed write
__global__ void out_kernel(const float* __restrict__ h5, const float* __restrict__ s,
                           const float* __restrict__ tt, float* __restrict__ out) {
  __shared__ float tile[32][33];
  int b = blockIdx.z;
  int n0 = blockIdx.x * 32, o0 = blockIdx.y * 32;
  int t = threadIdx.x;
  for (int e = t; e < 1024; e += 256) {
    int rn = e >> 5, co = e & 31;
    int o = o0 + co;
    float v = h5[((size_t)b * NPTS + n0 + rn) * 1024 + o] * s[o] + tt[o];
    tile[rn][co] = v > 0.f ? v : SLOPE * v;
  }
  __syncthreads();
  for (int e = t; e < 1024; e += 256) {
    int ro = e >> 5, cn = e & 31;
    out[((size_t)b * 1024 + o0 + ro) * NPTS + n0 + cn] = tile[cn][ro];
  }
}

// ---------------- host ----------------
extern "C" void kernel_launch(void* const* d_in, const int* in_sizes, int n_in,
                              void* d_out, int out_size, void* d_ws, size_t ws_size,
                              hipStream_t stream) {
  const float* x = (const float*)d_in[0];
  const float* Wm[5] = {(const float*)d_in[1], (const float*)d_in[4], (const float*)d_in[7],
                        (const float*)d_in[10], (const float*)d_in[13]};
  const float* gv[5] = {(const float*)d_in[2], (const float*)d_in[5], (const float*)d_in[8],
                        (const float*)d_in[11], (const float*)d_in[14]};
  const float* bvv[5] = {(const float*)d_in[3], (const float*)d_in[6], (const float*)d_in[9],
                         (const float*)d_in[12], (const float*)d_in[15]};
  float* out = (float*)d_out;

  char* wsb = (char*)d_ws;
  size_t off = 0;
  auto alloc = [&](size_t bytes) -> char* {
    off = (off + 255) & ~(size_t)255;
    char* p = wsb + off;
    off += bytes;
    return p;
  };
  float* xb = (float*)alloc((size_t)BATCH * NPTS * 3 * 4);
  float* xxb = (float*)alloc((size_t)BATCH * NPTS * 4);
  int* idxb = (int*)alloc((size_t)BATCH * NPTS * KNN * 4);
  float* feat = (float*)alloc((size_t)BATCH * NPTS * 512 * 4);
  float* hmax = (float*)alloc((size_t)BATCH * NPTS * 256 * 4);
  float* h5 = (float*)alloc((size_t)BATCH * NPTS * 1024 * 4);
  float* w1t = (float*)alloc(6 * 64 * 4);
  float* w2t = (float*)alloc(128 * 64 * 4);
  float* w3t = (float*)alloc(128 * 128 * 4);
  float* w4t = (float*)alloc(256 * 256 * 4);
  float* w5t = (float*)alloc(512 * 1024 * 4);
  float* stats = (float*)alloc(3072 * 4);
  float* stv = (float*)alloc(3072 * 4);
  off = (off + 255) & ~(size_t)255;
  size_t avail = (ws_size > off) ? (ws_size - off) : 0;
  size_t rmax = avail / ((size_t)NPTS * 4);
  int R;
  if (rmax >= NPTS) R = NPTS;
  else { R = (int)(rmax & ~(size_t)63); if (R < 64) R = 64; }
  float* distbuf = (float*)(wsb + off);

  float* ss[5] = {stats + 0, stats + 128, stats + 256, stats + 512, stats + 1024};
  float* sq[5] = {stats + 64, stats + 192, stats + 384, stats + 768, stats + 2048};
  float* sv[5] = {stv + 0, stv + 128, stv + 256, stv + 512, stv + 1024};
  float* tv[5] = {stv + 64, stv + 192, stv + 384, stv + 768, stv + 2048};
  float* wts[5] = {w1t, w2t, w3t, w4t, w5t};
  const int Os[5] = {64, 64, 128, 256, 1024};
  const int Is[5] = {6, 128, 128, 256, 512};

  zero_kernel<<<12, 256, 0, stream>>>(stats, 3072);
  xtrans_kernel<<<(BATCH * 3 * NPTS + 255) / 256, 256, 0, stream>>>(x, xb);
  for (int l = 0; l < 5; ++l)
    wtrans_kernel<<<(Os[l] * Is[l] + 255) / 256, 256, 0, stream>>>(Wm[l], wts[l], Os[l], Is[l]);

  auto knn = [&](const float* Xbase, int stride, int C) {
    xx_kernel<<<(BATCH * NPTS + 255) / 256, 256, 0, stream>>>(Xbase, stride, C, xxb);
    for (int b = 0; b < BATCH; ++b) {
      for (int n0 = 0; n0 < NPTS; n0 += R) {
        int rows = imin(R, NPTS - n0);
        dist_kernel<<<dim3(NPTS / 64, rows / 64), 256, 0, stream>>>(
            Xbase + (size_t)b * NPTS * stride, stride, C, xxb + (size_t)b * NPTS, distbuf, n0);
        topk_kernel<<<rows, 256, 0, stream>>>(distbuf, idxb + (size_t)b * NPTS * KNN, n0);
      }
    }
  };

  auto edge = [&](int li, const float* Xbase, int stride, int C, int O, int NOsel, int colOff) {
    knn(Xbase, stride, C);
    size_t lds = (size_t)(2 * C + 2 * KNN * C + 16 * O) * 4 + 2 * KNN * 4;
    dim3 eg(NPTS / 2, BATCH);
    if (NOsel == 1)
      edgeconv_kernel<1><<<eg, 128, lds, stream>>>(Xbase, stride, C, O, wts[li], idxb, hmax, ss[li], sq[li]);
    else if (NOsel == 2)
      edgeconv_kernel<2><<<eg, 128, lds, stream>>>(Xbase, stride, C, O, wts[li], idxb, hmax, ss[li], sq[li]);
    else
      edgeconv_kernel<4><<<eg, 128, lds, stream>>>(Xbase, stride, C, O, wts[li], idxb, hmax, ss[li], sq[li]);
    bn_finalize<<<(O + 255) / 256, 256, 0, stream>>>(ss[li], sq[li], gv[li], bvv[li],
                                                     1.f / ((float)BATCH * NPTS * KNN), O, sv[li], tv[li]);
    int logO = (O == 64) ? 6 : (O == 128) ? 7 : 8;
    int total = BATCH * NPTS * O;
    apply_kernel<<<(total + 255) / 256, 256, 0, stream>>>(hmax, sv[li], tv[li], feat, colOff, logO, total);
  };

  edge(0, xb, 3, 3, 64, 1, 0);
  edge(1, feat, 512, 64, 64, 1, 64);
  edge(2, feat + 64, 512, 64, 128, 2, 128);
  edge(3, feat + 128, 512, 128, 256, 4, 256);

  fc_kernel<<<dim3(BATCH * NPTS / 16, 4), 256, 0, stream>>>(feat, w5t, h5, ss[4], sq[4]);
  bn_finalize<<<4, 256, 0, stream>>>(ss[4], sq[4], gv[4], bvv[4], 1.f / ((float)BATCH * NPTS), 1024, sv[4], tv[4]);
  out_kernel<<<dim3(NPTS / 32, 1024 / 32, BATCH), 256, 0, stream>>>(h5, sv[4], tv[4], out);
}